// Round 1
// baseline (243.346 us; speedup 1.0000x reference)
//
#include <hip/hip_runtime.h>
#include <math.h>

#define B_    4
#define T_    20
#define N_    256
#define L_    5120      // T_*N_
#define CC_   32
#define CMAP_ 2048
#define HW_   256       // 16*16

__device__ __forceinline__ float fexp2(float x) { return __builtin_amdgcn_exp2f(x); }
__device__ __forceinline__ float frcp(float x)  { return __builtin_amdgcn_rcpf(x); }
// sigmoid(x) = 1/(1+e^-x)
__device__ __forceinline__ float sigm(float x)  { return frcp(1.f + fexp2(-1.44269504f * x)); }
// tanh(x) = 1 - 2/(e^{2x}+1)
__device__ __forceinline__ float tanh_(float x) { return 1.f - 2.f * frcp(fexp2(2.88539008f * x) + 1.f); }

// ---------------- K1: 1x1 conv compressor, c-split partials --------------
// grid: B*16*8 = 512 blocks x 256 thr.  pcm[cs][b][o][hw]
__global__ void __launch_bounds__(256) k_compress(const float* __restrict__ md,
                                                  const float* __restrict__ comp_w,
                                                  float* __restrict__ pcm) {
    __shared__ float wl[32 * 257];
    int blk = blockIdx.x;
    int cs = blk & 7;
    int h  = (blk >> 3) & 15;
    int b  = blk >> 7;
    int tid = threadIdx.x;
    int c0 = cs * 256;
    #pragma unroll
    for (int r = 0; r < 32; ++r)
        wl[r * 257 + tid] = comp_w[r * CMAP_ + c0 + tid];
    __syncthreads();
    int w = tid & 15, oo = tid >> 4;   // oo in [0,16)
    const float* mp = md + ((size_t)(b * CMAP_ + c0)) * HW_ + h * 16 + w;
    float a0 = 0.f, a1 = 0.f;
    #pragma unroll 4
    for (int cc = 0; cc < 256; ++cc) {
        float mv = mp[(size_t)cc * HW_];
        a0 += wl[oo * 257 + cc] * mv;
        a1 += wl[(oo + 16) * 257 + cc] * mv;
    }
    int hw = h * 16 + w;
    pcm[((cs * B_ + b) * CC_ + oo) * HW_ + hw]      = a0;
    pcm[((cs * B_ + b) * CC_ + oo + 16) * HW_ + hw] = a1;
}

// ---------------- K2: per-token LSTM + grid-sample + projections ---------
// grid: B*T = 80 blocks x 256 thr (thread = n)
__global__ void __launch_bounds__(256) k_token(const float* __restrict__ x,
        const float* __restrict__ pcm, const float* __restrict__ comp_b,
        const float* __restrict__ w_ih, const float* __restrict__ b_ih,
        const float* __restrict__ b_hh,
        const float* __restrict__ vf_w, const float* __restrict__ vf_b,
        const float* __restrict__ fc_w, const float* __restrict__ fc_b,
        const float* __restrict__ fc2_w, const float* __restrict__ fc2_b,
        const float* __restrict__ fc3_w, const float* __restrict__ fc3_b,
        float* __restrict__ Qg, float* __restrict__ Kg, float* __restrict__ Vg) {
    __shared__ float cml[CC_ * HW_];
    int blk = blockIdx.x;
    int b = blk / T_, t = blk % T_;
    int tid = threadIdx.x;
    // reduce the 8 c-split partials of cm[b] into LDS (+bias)
    for (int i = tid; i < CC_ * HW_; i += 256) {
        float s = comp_b[i >> 8];
        #pragma unroll
        for (int ps = 0; ps < 8; ++ps) s += pcm[(ps * B_ + b) * CC_ * HW_ + i];
        cml[i] = s;
    }
    __syncthreads();
    int n = tid;
    float xr0r = x[((b * 2 + 0) * T_ + t) * N_ + n];
    float xr1r = x[((b * 2 + 1) * T_ + t) * N_ + n];
    float xr0 = xr0r + sinf((float)t);
    float xr1 = xr1r + cosf((float)t);
    // single-step LSTM (h0=c0=0): gates i,f,g,o (f unused since c0=0)
    float Xh[4];
    #pragma unroll
    for (int k = 0; k < 4; ++k) {
        float ig = w_ih[(k)      * 2] * xr0 + w_ih[(k)      * 2 + 1] * xr1 + b_ih[k]      + b_hh[k];
        float gg = w_ih[(8 + k)  * 2] * xr0 + w_ih[(8 + k)  * 2 + 1] * xr1 + b_ih[8 + k]  + b_hh[8 + k];
        float og = w_ih[(12 + k) * 2] * xr0 + w_ih[(12 + k) * 2 + 1] * xr1 + b_ih[12 + k] + b_hh[12 + k];
        float c = sigm(ig) * tanh_(gg);
        Xh[k] = sigm(og) * tanh_(c);
    }
    // bilinear grid-sample coords (align_corners=False, zero pad)
    float ix = xr0r * 0.03125f - 0.5f;   // x/32 - 0.5
    float iy = xr1r * 0.03125f - 0.5f;
    float x0f = floorf(ix), y0f = floorf(iy);
    float wx1 = ix - x0f, wx0 = 1.f - wx1;
    float wy1 = iy - y0f, wy0 = 1.f - wy1;
    int x0 = (int)x0f, y0 = (int)y0f;
    int x1 = x0 + 1, y1 = y0 + 1;
    bool vx0 = (x0 >= 0) && (x0 <= 15), vx1 = (x1 >= 0) && (x1 <= 15);
    bool vy0 = (y0 >= 0) && (y0 <= 15), vy1 = (y1 >= 0) && (y1 <= 15);
    int cx0 = min(max(x0, 0), 15), cx1 = min(max(x1, 0), 15);
    int cy0 = min(max(y0, 0), 15), cy1 = min(max(y1, 0), 15);
    float wg0 = (vx0 && vy0) ? wx0 * wy0 : 0.f; int of0 = cy0 * 16 + cx0;
    float wg1 = (vx1 && vy0) ? wx1 * wy0 : 0.f; int of1 = cy0 * 16 + cx1;
    float wg2 = (vx0 && vy1) ? wx0 * wy1 : 0.f; int of2 = cy1 * 16 + cx0;
    float wg3 = (vx1 && vy1) ? wx1 * wy1 : 0.f; int of3 = cy1 * 16 + cx1;
    // vf: fused = [Xh(4), lc(32)]
    float X2[4];
    #pragma unroll
    for (int j = 0; j < 4; ++j)
        X2[j] = vf_b[j] + vf_w[j * 36 + 0] * Xh[0] + vf_w[j * 36 + 1] * Xh[1]
                        + vf_w[j * 36 + 2] * Xh[2] + vf_w[j * 36 + 3] * Xh[3];
    #pragma unroll 8
    for (int c = 0; c < 32; ++c) {
        const float* p = &cml[c * HW_];
        float lc = wg0 * p[of0] + wg1 * p[of1] + wg2 * p[of2] + wg3 * p[of3];
        #pragma unroll
        for (int j = 0; j < 4; ++j) X2[j] += vf_w[j * 36 + 4 + c] * lc;
    }
    int l = t * N_ + n;
    size_t obase = ((size_t)b * L_ + l) * 8;
    #pragma unroll
    for (int j = 0; j < 8; ++j) {
        Qg[obase + j] = fc_b[j] + fc_w[j * 4 + 0] * X2[0] + fc_w[j * 4 + 1] * X2[1]
                                + fc_w[j * 4 + 2] * X2[2] + fc_w[j * 4 + 3] * X2[3];
        Kg[obase + j] = fc2_b[j] + fc2_w[j * 2] * xr0 + fc2_w[j * 2 + 1] * xr1;
        Vg[obase + j] = fc3_b[j] + fc3_w[j * 2] * xr0 + fc3_w[j * 2 + 1] * xr1;
    }
}

// ---------------- K3: sigmoid attention, m-split partials ----------------
// grid: B*5*msplit blocks x 256 thr; 4 q-rows/thread (l-tile = 1024)
__global__ void __launch_bounds__(256) k_attn(const float* __restrict__ Qg,
        const float* __restrict__ Kg, const float* __restrict__ Vg,
        float* __restrict__ part, int msplit, int mchunk) {
    __shared__ __align__(16) float Kl[64 * 8];
    __shared__ __align__(16) float Vl[64 * 8];
    int blk = blockIdx.x;
    int ms = blk % msplit;
    int rest = blk / msplit;
    int lt = rest % 5, b = rest / 5;
    int tid = threadIdx.x;
    float q[4][8], acc[4][8];
    #pragma unroll
    for (int k = 0; k < 4; ++k) {
        int l = lt * 1024 + k * 256 + tid;
        const float4* qp = (const float4*)&Qg[((size_t)b * L_ + l) * 8];
        float4 qa = qp[0], qb = qp[1];
        q[k][0] = qa.x; q[k][1] = qa.y; q[k][2] = qa.z; q[k][3] = qa.w;
        q[k][4] = qb.x; q[k][5] = qb.y; q[k][6] = qb.z; q[k][7] = qb.w;
        #pragma unroll
        for (int d = 0; d < 8; ++d) acc[k][d] = 0.f;
    }
    int m0 = ms * mchunk;
    for (int mt = 0; mt < mchunk; mt += 64) {
        __syncthreads();
        if (tid < 128) {
            int row = tid >> 1, hf = (tid & 1) * 4;
            int m = m0 + mt + row;
            *(float4*)&Kl[row * 8 + hf] = *(const float4*)&Kg[((size_t)b * L_ + m) * 8 + hf];
        } else {
            int t2 = tid - 128;
            int row = t2 >> 1, hf = (t2 & 1) * 4;
            int m = m0 + mt + row;
            *(float4*)&Vl[row * 8 + hf] = *(const float4*)&Vg[((size_t)b * L_ + m) * 8 + hf];
        }
        __syncthreads();
        #pragma unroll 2
        for (int j = 0; j < 64; ++j) {
            float4 ka = *(const float4*)&Kl[j * 8];
            float4 kb = *(const float4*)&Kl[j * 8 + 4];
            float4 va = *(const float4*)&Vl[j * 8];
            float4 vb = *(const float4*)&Vl[j * 8 + 4];
            #pragma unroll
            for (int k = 0; k < 4; ++k) {
                float s = q[k][0] * ka.x + q[k][1] * ka.y + q[k][2] * ka.z + q[k][3] * ka.w
                        + q[k][4] * kb.x + q[k][5] * kb.y + q[k][6] * kb.z + q[k][7] * kb.w;
                float p = sigm(s);
                acc[k][0] += p * va.x; acc[k][1] += p * va.y;
                acc[k][2] += p * va.z; acc[k][3] += p * va.w;
                acc[k][4] += p * vb.x; acc[k][5] += p * vb.y;
                acc[k][6] += p * vb.z; acc[k][7] += p * vb.w;
            }
        }
    }
    #pragma unroll
    for (int k = 0; k < 4; ++k) {
        int l = lt * 1024 + k * 256 + tid;
        float4* pp = (float4*)&part[(((size_t)ms * B_ + b) * L_ + l) * 8];
        pp[0] = make_float4(acc[k][0], acc[k][1], acc[k][2], acc[k][3]);
        pp[1] = make_float4(acc[k][4], acc[k][5], acc[k][6], acc[k][7]);
    }
}

// ---------------- K4: reduce partials + threshold_relu + fco -------------
// grid: 80 blocks x 256 thr
__global__ void __launch_bounds__(256) k_final(const float* __restrict__ part,
        const float* __restrict__ fco_w, const float* __restrict__ fco_b,
        float* __restrict__ out, int msplit) {
    int p = blockIdx.x * 256 + threadIdx.x;
    int b = p / L_, l = p % L_;
    float a[8] = {0, 0, 0, 0, 0, 0, 0, 0};
    for (int s = 0; s < msplit; ++s) {
        const float4* pp = (const float4*)&part[(((size_t)s * B_ + b) * L_ + l) * 8];
        float4 u = pp[0], v = pp[1];
        a[0] += u.x; a[1] += u.y; a[2] += u.z; a[3] += u.w;
        a[4] += v.x; a[5] += v.y; a[6] += v.z; a[7] += v.w;
    }
    float o0 = fco_b[0], o1 = fco_b[1];
    #pragma unroll
    for (int d = 0; d < 8; ++d) {
        float od = a[d] > 0.5f ? a[d] : 0.f;   // o * (o > TH), TH=0.5
        o0 += fco_w[d] * od;
        o1 += fco_w[8 + d] * od;
    }
    int t = l >> 8, n = l & 255;
    out[((b * 2 + 0) * T_ + t) * N_ + n] = o0;
    out[((b * 2 + 1) * T_ + t) * N_ + n] = o1;
}

extern "C" void kernel_launch(void* const* d_in, const int* in_sizes, int n_in,
                              void* d_out, int out_size, void* d_ws, size_t ws_size,
                              hipStream_t stream) {
    const float* x      = (const float*)d_in[0];
    const float* md     = (const float*)d_in[1];
    const float* w_ih   = (const float*)d_in[2];
    const float* b_ih   = (const float*)d_in[3];
    const float* b_hh   = (const float*)d_in[4];
    const float* comp_w = (const float*)d_in[5];
    const float* comp_b = (const float*)d_in[6];
    const float* vf_w   = (const float*)d_in[7];
    const float* vf_b   = (const float*)d_in[8];
    const float* fc_w   = (const float*)d_in[9];
    const float* fc_b   = (const float*)d_in[10];
    const float* fc2_w  = (const float*)d_in[11];
    const float* fc2_b  = (const float*)d_in[12];
    const float* fc3_w  = (const float*)d_in[13];
    const float* fc3_b  = (const float*)d_in[14];
    const float* fco_w  = (const float*)d_in[15];
    const float* fco_b  = (const float*)d_in[16];

    float* ws   = (float*)d_ws;
    float* pcm  = ws;                    // 8*4*32*256      = 262144 floats
    float* Qg   = ws + 262144;           // 4*5120*8        = 163840
    float* Kg   = ws + 425984;           // 163840
    float* Vg   = ws + 589824;           // 163840
    float* part = ws + 753664;           // msplit*4*5120*8

    int msplit = 16;                     // shrink if workspace is small
    while (msplit > 1 && (753664 + (size_t)msplit * 163840) * 4 > ws_size) msplit >>= 1;
    int mchunk = L_ / msplit;            // multiple of 64 for all msplit in {16,8,4,2,1}

    hipLaunchKernelGGL(k_compress, dim3(512), dim3(256), 0, stream, md, comp_w, pcm);
    hipLaunchKernelGGL(k_token, dim3(B_ * T_), dim3(256), 0, stream, x, pcm, comp_b,
                       w_ih, b_ih, b_hh, vf_w, vf_b, fc_w, fc_b,
                       fc2_w, fc2_b, fc3_w, fc3_b, Qg, Kg, Vg);
    hipLaunchKernelGGL(k_attn, dim3(B_ * 5 * msplit), dim3(256), 0, stream,
                       Qg, Kg, Vg, part, msplit, mchunk);
    hipLaunchKernelGGL(k_final, dim3(B_ * T_), dim3(256), 0, stream,
                       part, fco_w, fco_b, (float*)d_out, msplit);
}

// Round 8
// 169.372 us; speedup vs baseline: 1.4368x; 1.4368x over previous
//
#include <hip/hip_runtime.h>
#include <math.h>

#define B_    4
#define T_    20
#define N_    256
#define L_    5120      // T_*N_
#define CC_   32
#define CMAP_ 2048
#define HW_   256       // 16*16

__device__ __forceinline__ float fexp2(float x) { return __builtin_amdgcn_exp2f(x); }
__device__ __forceinline__ float frcp(float x)  { return __builtin_amdgcn_rcpf(x); }
__device__ __forceinline__ float sigm(float x)  { return frcp(1.f + fexp2(-1.44269504f * x)); }
__device__ __forceinline__ float tanh_(float x) { return 1.f - 2.f * frcp(fexp2(2.88539008f * x) + 1.f); }

// ---------------- K1: 1x1 conv compressor, c-split partials --------------
// grid: B*16*8 = 512 blocks x 256 thr.  pcm[cs][b][o][hw]
__global__ void __launch_bounds__(256) k_compress(const float* __restrict__ md,
                                                  const float* __restrict__ comp_w,
                                                  float* __restrict__ pcm) {
    __shared__ float wl[32 * 257];
    int blk = blockIdx.x;
    int cs = blk & 7;
    int h  = (blk >> 3) & 15;
    int b  = blk >> 7;
    int tid = threadIdx.x;
    int c0 = cs * 256;
    #pragma unroll
    for (int r = 0; r < 32; ++r)
        wl[r * 257 + tid] = comp_w[r * CMAP_ + c0 + tid];
    __syncthreads();
    int w = tid & 15, oo = tid >> 4;   // oo in [0,16)
    const float* mp = md + ((size_t)(b * CMAP_ + c0)) * HW_ + h * 16 + w;
    float a0 = 0.f, a1 = 0.f;
    #pragma unroll 4
    for (int cc = 0; cc < 256; ++cc) {
        float mv = mp[(size_t)cc * HW_];
        a0 += wl[oo * 257 + cc] * mv;
        a1 += wl[(oo + 16) * 257 + cc] * mv;
    }
    int hw = h * 16 + w;
    pcm[((cs * B_ + b) * CC_ + oo) * HW_ + hw]      = a0;
    pcm[((cs * B_ + b) * CC_ + oo + 16) * HW_ + hw] = a1;
}

// ---------------- K1b: reduce c-split partials + bias -> cm --------------
// grid: 128 blocks x 256 thr over B*CC*HW = 32768 elements
__global__ void __launch_bounds__(256) k_reduce_cm(const float* __restrict__ pcm,
                                                   const float* __restrict__ comp_b,
                                                   float* __restrict__ cm) {
    int i = blockIdx.x * 256 + threadIdx.x;   // i = ((b*32+o)*256+hw)
    float s = comp_b[(i >> 8) & 31];
    #pragma unroll
    for (int ps = 0; ps < 8; ++ps) s += pcm[ps * (B_ * CC_ * HW_) + i];
    cm[i] = s;
}

// ---------------- K2: per-token LSTM + grid-sample + projections ---------
// -> ABC (score coefficients) and XM (pe'd coords). grid: 160 x 128
__global__ void __launch_bounds__(128) k_token(const float* __restrict__ x,
        const float* __restrict__ cm,
        const float* __restrict__ w_ih, const float* __restrict__ b_ih,
        const float* __restrict__ b_hh,
        const float* __restrict__ vf_w, const float* __restrict__ vf_b,
        const float* __restrict__ fc_w, const float* __restrict__ fc_b,
        const float* __restrict__ fc2_w, const float* __restrict__ fc2_b,
        float4* __restrict__ ABC, float2* __restrict__ XM) {
    int p = blockIdx.x * 128 + threadIdx.x;   // [0, B*L)
    int b = p / L_;
    int l = p - b * L_;
    int t = l >> 8, n = l & 255;
    float x0r = x[((b * 2 + 0) * T_ + t) * N_ + n];
    float x1r = x[((b * 2 + 1) * T_ + t) * N_ + n];
    float xr0 = x0r + sinf((float)t);
    float xr1 = x1r + cosf((float)t);
    // single-step LSTM (h0=c0=0)
    float Xh[4];
    #pragma unroll
    for (int k = 0; k < 4; ++k) {
        float ig = w_ih[(k)      * 2] * xr0 + w_ih[(k)      * 2 + 1] * xr1 + b_ih[k]      + b_hh[k];
        float gg = w_ih[(8 + k)  * 2] * xr0 + w_ih[(8 + k)  * 2 + 1] * xr1 + b_ih[8 + k]  + b_hh[8 + k];
        float og = w_ih[(12 + k) * 2] * xr0 + w_ih[(12 + k) * 2 + 1] * xr1 + b_ih[12 + k] + b_hh[12 + k];
        float c = sigm(ig) * tanh_(gg);
        Xh[k] = sigm(og) * tanh_(c);
    }
    // bilinear grid-sample on RAW coords (align_corners=False, zero pad)
    float ix = x0r * 0.03125f - 0.5f;
    float iy = x1r * 0.03125f - 0.5f;
    float x0f = floorf(ix), y0f = floorf(iy);
    float wx1 = ix - x0f, wx0 = 1.f - wx1;
    float wy1 = iy - y0f, wy0 = 1.f - wy1;
    int x0 = (int)x0f, y0 = (int)y0f;
    int x1 = x0 + 1, y1 = y0 + 1;
    bool vx0 = (x0 >= 0) && (x0 <= 15), vx1 = (x1 >= 0) && (x1 <= 15);
    bool vy0 = (y0 >= 0) && (y0 <= 15), vy1 = (y1 >= 0) && (y1 <= 15);
    int cx0 = min(max(x0, 0), 15), cx1 = min(max(x1, 0), 15);
    int cy0 = min(max(y0, 0), 15), cy1 = min(max(y1, 0), 15);
    float wg0 = (vx0 && vy0) ? wx0 * wy0 : 0.f; int of0 = cy0 * 16 + cx0;
    float wg1 = (vx1 && vy0) ? wx1 * wy0 : 0.f; int of1 = cy0 * 16 + cx1;
    float wg2 = (vx0 && vy1) ? wx0 * wy1 : 0.f; int of2 = cy1 * 16 + cx0;
    float wg3 = (vx1 && vy1) ? wx1 * wy1 : 0.f; int of3 = cy1 * 16 + cx1;
    // vf: fused = [Xh(4), lc(32)]
    float X2[4];
    #pragma unroll
    for (int j = 0; j < 4; ++j)
        X2[j] = vf_b[j] + vf_w[j * 36 + 0] * Xh[0] + vf_w[j * 36 + 1] * Xh[1]
                        + vf_w[j * 36 + 2] * Xh[2] + vf_w[j * 36 + 3] * Xh[3];
    const float* cmb = cm + (size_t)b * CC_ * HW_;
    #pragma unroll 8
    for (int c = 0; c < 32; ++c) {
        const float* pch = cmb + c * HW_;
        float lc = wg0 * pch[of0] + wg1 * pch[of1] + wg2 * pch[of2] + wg3 * pch[of3];
        #pragma unroll
        for (int j = 0; j < 4; ++j) X2[j] += vf_w[j * 36 + 4 + c] * lc;
    }
    // Q = fc(X2); fold through fc2 into rank-2 score coefficients
    float A = 0.f, Bv = 0.f, C = 0.f;
    #pragma unroll
    for (int j = 0; j < 8; ++j) {
        float Qj = fc_b[j] + fc_w[j * 4 + 0] * X2[0] + fc_w[j * 4 + 1] * X2[1]
                           + fc_w[j * 4 + 2] * X2[2] + fc_w[j * 4 + 3] * X2[3];
        A  += Qj * fc2_w[j * 2 + 0];
        Bv += Qj * fc2_w[j * 2 + 1];
        C  += Qj * fc2_b[j];
    }
    ABC[p] = make_float4(A, Bv, C, 0.f);
    XM[p]  = make_float2(xr0, xr1);
}

// ---------------- K3: rank-2 sigmoid attention, m-split partials ---------
// grid: B*5*msplit blocks x 256 thr; 4 q-rows/thread (l-tile = 1024)
// part[ms][b][l] = float4(S0, S1, Sp, 0) with S0=sum p*x0, S1=sum p*x1, Sp=sum p
__global__ void __launch_bounds__(256) k_attn(const float4* __restrict__ ABC,
        const float2* __restrict__ XM, float4* __restrict__ part,
        int msplit, int mchunk) {
    int blk = blockIdx.x;
    int ms = blk % msplit;
    int rest = blk / msplit;
    int lt = rest % 5, b = rest / 5;
    int tid = threadIdx.x;
    float A[4], Bv[4], C[4], S0[4], S1[4], Sp[4];
    #pragma unroll
    for (int k = 0; k < 4; ++k) {
        int l = lt * 1024 + k * 256 + tid;
        float4 abc = ABC[(size_t)b * L_ + l];
        A[k] = abc.x; Bv[k] = abc.y; C[k] = abc.z;
        S0[k] = 0.f; S1[k] = 0.f; Sp[k] = 0.f;
    }
    const float2* xp = XM + (size_t)b * L_ + (size_t)ms * mchunk;
    #pragma unroll 4
    for (int j = 0; j < mchunk; ++j) {
        float2 xm = xp[j];   // wave-uniform -> scalarizable / L1 broadcast
        #pragma unroll
        for (int k = 0; k < 4; ++k) {
            float s = fmaf(A[k], xm.x, fmaf(Bv[k], xm.y, C[k]));
            float pb = sigm(s);
            S0[k] = fmaf(pb, xm.x, S0[k]);
            S1[k] = fmaf(pb, xm.y, S1[k]);
            Sp[k] += pb;
        }
    }
    #pragma unroll
    for (int k = 0; k < 4; ++k) {
        int l = lt * 1024 + k * 256 + tid;
        part[((size_t)ms * B_ + b) * L_ + l] = make_float4(S0[k], S1[k], Sp[k], 0.f);
    }
}

// ---------------- K4: reduce partials + V-reconstruct + trelu + fco ------
// grid: 160 blocks x 128 thr over B*L threads
__global__ void __launch_bounds__(128) k_final(const float4* __restrict__ part,
        const float* __restrict__ fc3_w, const float* __restrict__ fc3_b,
        const float* __restrict__ fco_w, const float* __restrict__ fco_b,
        float* __restrict__ out, int msplit) {
    int p = blockIdx.x * 128 + threadIdx.x;
    int b = p / L_, l = p - b * L_;
    float s0 = 0.f, s1 = 0.f, sp = 0.f;
    for (int s = 0; s < msplit; ++s) {
        float4 u = part[((size_t)s * B_ + b) * L_ + l];
        s0 += u.x; s1 += u.y; sp += u.z;
    }
    float o0 = fco_b[0], o1 = fco_b[1];
    #pragma unroll
    for (int d = 0; d < 8; ++d) {
        float od = fc3_w[d * 2 + 0] * s0 + fc3_w[d * 2 + 1] * s1 + fc3_b[d] * sp;
        od = od > 0.5f ? od : 0.f;   // threshold_relu, TH=0.5
        o0 += fco_w[d] * od;
        o1 += fco_w[8 + d] * od;
    }
    int t = l >> 8, n = l & 255;
    out[((b * 2 + 0) * T_ + t) * N_ + n] = o0;
    out[((b * 2 + 1) * T_ + t) * N_ + n] = o1;
}

extern "C" void kernel_launch(void* const* d_in, const int* in_sizes, int n_in,
                              void* d_out, int out_size, void* d_ws, size_t ws_size,
                              hipStream_t stream) {
    const float* x      = (const float*)d_in[0];
    const float* md     = (const float*)d_in[1];
    const float* w_ih   = (const float*)d_in[2];
    const float* b_ih   = (const float*)d_in[3];
    const float* b_hh   = (const float*)d_in[4];
    const float* comp_w = (const float*)d_in[5];
    const float* comp_b = (const float*)d_in[6];
    const float* vf_w   = (const float*)d_in[7];
    const float* vf_b   = (const float*)d_in[8];
    const float* fc_w   = (const float*)d_in[9];
    const float* fc_b   = (const float*)d_in[10];
    const float* fc2_w  = (const float*)d_in[11];
    const float* fc2_b  = (const float*)d_in[12];
    const float* fc3_w  = (const float*)d_in[13];
    const float* fc3_b  = (const float*)d_in[14];
    const float* fco_w  = (const float*)d_in[15];
    const float* fco_b  = (const float*)d_in[16];

    float* ws = (float*)d_ws;
    float*  pcm  = ws;                       // 8*B*32*256      = 262144 floats
    float*  cm   = ws + 262144;              // B*32*256        = 32768
    float4* ABC  = (float4*)(ws + 294912);   // B*L float4      = 81920 floats
    float2* XM   = (float2*)(ws + 376832);   // B*L float2      = 40960 floats
    float4* part = (float4*)(ws + 417792);   // msplit*B*L float4

    int msplit = 64;                         // 5120 % 64 == 0; shrink if ws small
    while (msplit > 1 && (417792 + (size_t)msplit * 81920) * 4 > ws_size) msplit >>= 1;
    int mchunk = L_ / msplit;

    hipLaunchKernelGGL(k_compress, dim3(512), dim3(256), 0, stream, md, comp_w, pcm);
    hipLaunchKernelGGL(k_reduce_cm, dim3(128), dim3(256), 0, stream, pcm, comp_b, cm);
    hipLaunchKernelGGL(k_token, dim3(160), dim3(128), 0, stream, x, cm,
                       w_ih, b_ih, b_hh, vf_w, vf_b, fc_w, fc_b,
                       fc2_w, fc2_b, ABC, XM);
    hipLaunchKernelGGL(k_attn, dim3(B_ * 5 * msplit), dim3(256), 0, stream,
                       ABC, XM, part, msplit, mchunk);
    hipLaunchKernelGGL(k_final, dim3(160), dim3(128), 0, stream,
                       part, fc3_w, fc3_b, fco_w, fco_b, (float*)d_out, msplit);
}